// Round 10
// baseline (305.868 us; speedup 1.0000x reference)
//
#include <hip/hip_runtime.h>
#include <hip/hip_bf16.h>
#include <stdint.h>

#define BATCH  8192
#define DIN    2048
#define DOUT   2048
#define NB     256
#define KSEL   26      // ceil(0.1*256)
#define GDELTA 1e-4f   // top-k boundary refine threshold

typedef __attribute__((ext_vector_type(4))) float f32x4;
typedef __attribute__((ext_vector_type(8))) __bf16 bf16x8;
typedef __attribute__((ext_vector_type(8))) unsigned short u16x8;

__device__ __forceinline__ float bf2f(unsigned short u){
  union { unsigned int i; float f; } v; v.i = ((unsigned int)u) << 16; return v.f;
}
__device__ __forceinline__ unsigned short f2bf_c(float f){
  __bf16 b = (__bf16)f;
  union { __bf16 b; unsigned short u; } v; v.b = b; return v.u;
}
// async global->LDS, 16B/lane; LDS dest wave-uniform base.
__device__ __forceinline__ void gload16(const unsigned short* g, unsigned short* l){
  __builtin_amdgcn_global_load_lds(
      (const __attribute__((address_space(1))) void*)g,
      (__attribute__((address_space(3))) void*)l, 16, 0, 0);
}

// BK=32 tile images (T21): elem (row, k) of a [R][32] bf16 tile at u16 offset
// row*32 + ((c3 ^ ((row>>1)&3))<<3) + (k&7), c3 = (k&31)>>3. Frag reads
// (16 rows x b128) land 2-way per bank = free. Same image in global so
// global_load_lds with linear dest reproduces it byte-for-byte.

// ---------------- K0a: x -> tiled hi/lo bf16 (xht = bf16(x), xlt = resid) ---
__global__ __launch_bounds__(256) void conv_xhl(const float* __restrict__ x,
    unsigned short* __restrict__ xht, unsigned short* __restrict__ xlt)
{
  const int r    = threadIdx.x >> 2;        // 0..63
  const int cq   = threadIdx.x & 3;
  const int grow = blockIdx.x * 64 + r;
  const int kp   = (blockIdx.y << 2) + cq;  // global 32k-step 0..63
  const int lrow = grow & 127;
  const int sw   = (lrow >> 1) & 3;
  const size_t base = ((size_t)(grow >> 7) * 64 + kp) * 4096 + lrow * 32;
  const float* xp = &x[(size_t)grow * DIN + kp * 32];
  #pragma unroll
  for (int c3 = 0; c3 < 4; c3++){
    f32x4 a0 = *(const f32x4*)(xp + c3 * 8);
    f32x4 a1 = *(const f32x4*)(xp + c3 * 8 + 4);
    u16x8 hi, lo;
    #pragma unroll
    for (int j = 0; j < 4; j++){
      const __bf16 h0 = (__bf16)a0[j];
      const __bf16 h1 = (__bf16)a1[j];
      union { __bf16 b; unsigned short u; } u0, u1; u0.b = h0; u1.b = h1;
      hi[j] = u0.u; hi[4 + j] = u1.u;
      lo[j]     = f2bf_c(a0[j] - (float)h0);
      lo[4 + j] = f2bf_c(a1[j] - (float)h1);
    }
    const int off = (c3 ^ sw) << 3;
    *(u16x8*)&xht[base + off] = hi;
    *(u16x8*)&xlt[base + off] = lo;
  }
}

// ---------------- K0b: W -> tiled-swizzled bf16 [q][kp][128*32] -------------
__global__ __launch_bounds__(256) void conv_wt2(const float* __restrict__ w,
                                                unsigned short* __restrict__ wtt)
{
  __shared__ float tl[64][65];
  const int k0 = blockIdx.x * 64;
  const int n0 = blockIdx.y * 64;
  const int c  = threadIdx.x & 63;
  const int r4 = threadIdx.x >> 6;
  #pragma unroll
  for (int i = 0; i < 16; i++){
    const int r = r4 * 16 + i;
    tl[r][c] = w[(size_t)(k0 + r) * DOUT + n0 + c];
  }
  __syncthreads();
  const int n  = threadIdx.x & 63;
  const int cp = threadIdx.x >> 6;
  const int gn = n0 + n;
  const int q  = gn >> 7;
  const int ln = gn & 127;
  const int sw = (ln >> 1) & 3;
  #pragma unroll
  for (int u = 0; u < 2; u++){
    const int cc = cp * 2 + u;              // 8k-chunk within 64k
    const int kp = (k0 >> 5) + (cc >> 2);
    const int c3 = cc & 3;
    u16x8 o;
    #pragma unroll
    for (int j = 0; j < 8; j++) o[j] = f2bf_c(tl[cc * 8 + j][n]);
    *(u16x8*)&wtt[((size_t)q * 64 + kp) * 4096 + ln * 32 + ((c3 ^ sw) << 3)] = o;
  }
}

// ---------------- K0c: gw -> tiled-swizzled hi/lo [ct][kp][64*32] -----------
__global__ __launch_bounds__(256) void conv_gwt2(const float* __restrict__ gw,
    unsigned short* __restrict__ ght, unsigned short* __restrict__ glt)
{
  __shared__ float tl[64][65];
  const int k0 = blockIdx.x * 64;
  const int c0 = blockIdx.y * 64;
  const int c  = threadIdx.x & 63;
  const int r4 = threadIdx.x >> 6;
  #pragma unroll
  for (int i = 0; i < 16; i++){
    const int r = r4 * 16 + i;
    tl[r][c] = gw[(size_t)(k0 + r) * NB + c0 + c];
  }
  __syncthreads();
  const int ln = threadIdx.x & 63;
  const int cp = threadIdx.x >> 6;
  const int ct = blockIdx.y;
  const int sw = (ln >> 1) & 3;
  #pragma unroll
  for (int u = 0; u < 2; u++){
    const int cc = cp * 2 + u;
    const int kp = (k0 >> 5) + (cc >> 2);
    const int c3 = cc & 3;
    u16x8 hi, lo;
    #pragma unroll
    for (int j = 0; j < 8; j++){
      const float v = tl[cc * 8 + j][ln];
      const __bf16 hb = (__bf16)v;
      union { __bf16 b; unsigned short u; } uh; uh.b = hb;
      hi[j] = uh.u;
      lo[j] = f2bf_c(v - (float)hb);
    }
    const size_t base = ((size_t)ct * 64 + kp) * 2048 + ln * 32;
    const int off = (c3 ^ sw) << 3;
    *(u16x8*)&ght[base + off] = hi;
    *(u16x8*)&glt[base + off] = lo;
  }
}

// ---------------- K1: gate GEMM, pure-DMA 3-term hi/lo bf16 MFMA ------------
// Block 128b x 64c, 4 waves (64b x 32c), BK=32, K-split 2. All operands via
// global_load_lds dbuf from pre-swizzled tiles: ZERO staging VALU in loop.
// Term order per (m,n): xh*gh, xl*gh, xh*gl — identical chain to R9.
__global__ __launch_bounds__(256) void gate_v5(
    const unsigned short* __restrict__ xht,
    const unsigned short* __restrict__ xlt,
    const unsigned short* __restrict__ ght,
    const unsigned short* __restrict__ glt,
    float* __restrict__ part)
{
  __shared__ unsigned short Ah[2][4096], Al[2][4096];  // 32 KB
  __shared__ unsigned short Bh[2][2048], Bl[2][2048];  // 16 KB

  const int bt   = blockIdx.x;          // 128-row b-tile
  const int b0   = bt * 128;
  const int ct   = blockIdx.y;
  const int z    = blockIdx.z;
  const int t    = threadIdx.x;
  const int lane = t & 63;
  const int wid  = t >> 6;
  const int bw   = wid & 1;
  const int cw   = wid >> 1;
  const int l15  = lane & 15;
  const int l4   = lane >> 4;

  const unsigned short* axh = xht + ((size_t)bt * 64 + z * 32) * 4096;
  const unsigned short* axl = xlt + ((size_t)bt * 64 + z * 32) * 4096;
  const unsigned short* bgh = ght + ((size_t)ct * 64 + z * 32) * 2048;
  const unsigned short* bgl = glt + ((size_t)ct * 64 + z * 32) * 2048;

  f32x4 acc[4][2];
  #pragma unroll
  for (int m = 0; m < 4; m++)
    #pragma unroll
    for (int n = 0; n < 2; n++) acc[m][n] = (f32x4)0.0f;

  int aoff[4], boff[2];
  #pragma unroll
  for (int m = 0; m < 4; m++){
    const int row = bw * 64 + m * 16 + l15;
    aoff[m] = row * 32 + ((l4 ^ ((row >> 1) & 3)) << 3);
  }
  #pragma unroll
  for (int n = 0; n < 2; n++){
    const int row = cw * 32 + n * 16 + l15;
    boff[n] = row * 32 + ((l4 ^ ((row >> 1) & 3)) << 3);
  }

  auto GLOAD = [&](int bb, int s){
    #pragma unroll
    for (int i = 0; i < 2; i++){
      const int sl = (wid * 2 + i) * 512;
      gload16(axh + (size_t)s * 4096 + sl + lane * 8, &Ah[bb][sl]);
      gload16(axl + (size_t)s * 4096 + sl + lane * 8, &Al[bb][sl]);
    }
    const int slb = wid * 512;
    gload16(bgh + (size_t)s * 2048 + slb + lane * 8, &Bh[bb][slb]);
    gload16(bgl + (size_t)s * 2048 + slb + lane * 8, &Bl[bb][slb]);
  };

  GLOAD(0, 0);
  int buf = 0;
  #pragma unroll 1
  for (int s = 0; s < 32; s++){
    __syncthreads();                    // DMA(buf) drained; prev compute done
    if (s < 31) GLOAD(buf ^ 1, s + 1);
    bf16x8 ah[4], al[4], bh[2], bl[2];
    #pragma unroll
    for (int m = 0; m < 4; m++){
      ah[m] = *(const bf16x8*)&Ah[buf][aoff[m]];
      al[m] = *(const bf16x8*)&Al[buf][aoff[m]];
    }
    #pragma unroll
    for (int n = 0; n < 2; n++){
      bh[n] = *(const bf16x8*)&Bh[buf][boff[n]];
      bl[n] = *(const bf16x8*)&Bl[buf][boff[n]];
    }
    #pragma unroll
    for (int m = 0; m < 4; m++)
      #pragma unroll
      for (int n = 0; n < 2; n++){
        acc[m][n] = __builtin_amdgcn_mfma_f32_16x16x32_bf16(ah[m], bh[n], acc[m][n], 0, 0, 0);
        acc[m][n] = __builtin_amdgcn_mfma_f32_16x16x32_bf16(al[m], bh[n], acc[m][n], 0, 0, 0);
        acc[m][n] = __builtin_amdgcn_mfma_f32_16x16x32_bf16(ah[m], bl[n], acc[m][n], 0, 0, 0);
      }
    buf ^= 1;
  }

  float* dst = part + (size_t)z * BATCH * NB;
  #pragma unroll
  for (int m = 0; m < 4; m++){
    const int brow = b0 + bw * 64 + m * 16 + l4 * 4;
    #pragma unroll
    for (int n = 0; n < 2; n++){
      const int ccol = ct * 64 + cw * 32 + n * 16 + l15;
      #pragma unroll
      for (int r = 0; r < 4; r++)
        dst[(size_t)(brow + r) * NB + ccol] = acc[m][n][r];
    }
  }
}

// ---------------- K2: sum 2 partials, top-26 + renorm + boundary flag -------
__global__ __launch_bounds__(256) void topk(float* __restrict__ part,
    const float* __restrict__ gb, int* __restrict__ flags)
{
  const int lane = threadIdx.x & 63;
  const int row  = blockIdx.x * 4 + (threadIdx.x >> 6);
  f32x4* p0 = (f32x4*)&part[(size_t)row * NB];
  const f32x4* p1 = (const f32x4*)&part[(size_t)(BATCH + row) * NB];
  const f32x4* gbv = (const f32x4*)gb;
  f32x4 v = p0[lane] + p1[lane] + gbv[lane];

  const float NEG = -3.402823466e38f;
  float w0 = v[0], w1 = v[1], w2 = v[2], w3 = v[3];
  float thr = 0.f, nxt = 0.f;
  for (int it = 0; it < KSEL + 1; it++){
    float lm = fmaxf(fmaxf(w0, w1), fmaxf(w2, w3));
    float wm = lm;
    #pragma unroll
    for (int off = 32; off; off >>= 1) wm = fmaxf(wm, __shfl_xor(wm, off, 64));
    unsigned long long ball = __ballot(lm == wm);
    int first = __ffsll(ball) - 1;
    if (lane == first){
      if      (w0 == wm) w0 = NEG;
      else if (w1 == wm) w1 = NEG;
      else if (w2 == wm) w2 = NEG;
      else               w3 = NEG;
    }
    if (it < KSEL) thr = wm; else nxt = wm;
  }
  if (lane == 0) flags[row] = (thr - nxt < GDELTA) ? 1 : 0;

  float s = 0.f;
  #pragma unroll
  for (int j = 0; j < 4; j++) s += (v[j] >= thr) ? v[j] : 0.f;
  #pragma unroll
  for (int off = 32; off; off >>= 1) s += __shfl_xor(s, off, 64);
  const float d = s * (1.0f / NB);
  f32x4 o;
  #pragma unroll
  for (int j = 0; j < 4; j++) o[j] = (v[j] >= thr) ? v[j] / d : 0.f;
  p0[lane] = o;
}

// ---------------- K2b: exact recompute of boundary-ambiguous rows -----------
__global__ __launch_bounds__(256) void refine(
    const float* __restrict__ x, const float* __restrict__ gw,
    const float* __restrict__ gb, const int* __restrict__ flags,
    float* __restrict__ part)
{
  const int lane = threadIdx.x & 63;
  const int row  = blockIdx.x * 4 + (threadIdx.x >> 6);
  if (!flags[row]) return;

  f32x4 acc0 = (f32x4)0.f, acc1 = (f32x4)0.f;
  const float* xp = &x[(size_t)row * DIN];
  #pragma unroll 8
  for (int k = 0; k < 1024; k++){
    const float xv = xp[k];
    const f32x4 wv = *(const f32x4*)&gw[(size_t)k * NB + lane * 4];
    #pragma unroll
    for (int j = 0; j < 4; j++) acc0[j] = fmaf(xv, wv[j], acc0[j]);
  }
  #pragma unroll 8
  for (int k = 1024; k < 2048; k++){
    const float xv = xp[k];
    const f32x4 wv = *(const f32x4*)&gw[(size_t)k * NB + lane * 4];
    #pragma unroll
    for (int j = 0; j < 4; j++) acc1[j] = fmaf(xv, wv[j], acc1[j]);
  }
  const f32x4 gbv = *(const f32x4*)&gb[lane * 4];
  f32x4 v;
  #pragma unroll
  for (int j = 0; j < 4; j++) v[j] = acc0[j] + acc1[j] + gbv[j];

  const float NEG = -3.402823466e38f;
  float w0 = v[0], w1 = v[1], w2 = v[2], w3 = v[3];
  float thr = 0.f;
  for (int it = 0; it < KSEL; it++){
    float lm = fmaxf(fmaxf(w0, w1), fmaxf(w2, w3));
    float wm = lm;
    #pragma unroll
    for (int off = 32; off; off >>= 1) wm = fmaxf(wm, __shfl_xor(wm, off, 64));
    unsigned long long ball = __ballot(lm == wm);
    int first = __ffsll(ball) - 1;
    if (lane == first){
      if      (w0 == wm) w0 = NEG;
      else if (w1 == wm) w1 = NEG;
      else if (w2 == wm) w2 = NEG;
      else               w3 = NEG;
    }
    thr = wm;
  }
  float s = 0.f;
  #pragma unroll
  for (int j = 0; j < 4; j++) s += (v[j] >= thr) ? v[j] : 0.f;
  #pragma unroll
  for (int off = 32; off; off >>= 1) s += __shfl_xor(s, off, 64);
  const float d = s * (1.0f / NB);
  f32x4 o;
  #pragma unroll
  for (int j = 0; j < 4; j++) o[j] = (v[j] >= thr) ? v[j] / d : 0.f;
  *(f32x4*)&part[(size_t)row * NB + lane * 4] = o;
}

// ---------------- K3: main GEMM, BK=32 m97 template + cheap p-fold ----------
// 128b x 128n (one q), 4 waves 64x64, gload_lds dbuf (LDS 40.7 KB, 3 blk/CU).
// p-slice = 4 steps: first MFMA of slice uses zero-C (no accP zeroing movs);
// fold accT += g*accP: 4x ds_read_b128 (gl2 [p][row]) + 64-float vector ops.
__global__ __launch_bounds__(256) void main_v4(
    const unsigned short* __restrict__ xht,
    const unsigned short* __restrict__ wtt,
    const float* __restrict__ g,
    const float* __restrict__ bias,
    float* __restrict__ out)
{
  __shared__ unsigned short XA[2][4096], WB[2][4096];  // 32 KB
  __shared__ float gl2[16 * 132];                      // [p][row], 8.4 KB

  const int f  = blockIdx.x;
  const int q  = f >> 6;
  const int bt = (f & 7) * 8 + ((f >> 3) & 7);   // XCD-aware: q-mates co-XCD
  const int b0 = bt * 128;
  const int t    = threadIdx.x;
  const int lane = t & 63;
  const int wid  = t >> 6;
  const int wr   = (wid >> 1) * 64;
  const int wc   = (wid & 1) * 64;
  const int l15  = lane & 15;
  const int l4   = lane >> 4;

  for (int e = t; e < 16 * 128; e += 256){
    const int p = e >> 7, r = e & 127;
    gl2[p * 132 + r] = g[(size_t)(b0 + r) * NB + p * 16 + q];
  }

  f32x4 accT[4][4];
  #pragma unroll
  for (int m = 0; m < 4; m++)
    #pragma unroll
    for (int n = 0; n < 4; n++) accT[m][n] = (f32x4)0.0f;
  const f32x4 z4 = (f32x4)0.0f;

  int aoff[4], boff[4];
  #pragma unroll
  for (int m = 0; m < 4; m++){
    const int row = wr + m * 16 + l15;
    aoff[m] = row * 32 + ((l4 ^ ((row >> 1) & 3)) << 3);
  }
  #pragma unroll
  for (int n = 0; n < 4; n++){
    const int row = wc + n * 16 + l15;
    boff[n] = row * 32 + ((l4 ^ ((row >> 1) & 3)) << 3);
  }

  const unsigned short* asrc0 = xht + (size_t)bt * 64 * 4096;
  const unsigned short* bsrc0 = wtt + (size_t)q  * 64 * 4096;

  auto GLOAD = [&](int bb, int kp){
    const unsigned short* as = asrc0 + (size_t)kp * 4096;
    const unsigned short* bs = bsrc0 + (size_t)kp * 4096;
    #pragma unroll
    for (int i = 0; i < 2; i++){
      const int sl = (wid * 2 + i) * 512;
      gload16(as + sl + lane * 8, &XA[bb][sl]);
      gload16(bs + sl + lane * 8, &WB[bb][sl]);
    }
  };

  GLOAD(0, 0);
  int buf = 0;
  #pragma unroll 1
  for (int pb = 0; pb < 16; pb++){
    f32x4 accP[4][4];
    #pragma unroll
    for (int s4 = 0; s4 < 4; s4++){
      const int kp = pb * 4 + s4;
      __syncthreads();                  // DMA(buf) drained; prev reads done
      if (kp < 63) GLOAD(buf ^ 1, kp + 1);
      bf16x8 a[4], b[4];
      #pragma unroll
      for (int m = 0; m < 4; m++) a[m] = *(const bf16x8*)&XA[buf][aoff[m]];
      #pragma unroll
      for (int n = 0; n < 4; n++) b[n] = *(const bf16x8*)&WB[buf][boff[n]];
      if (s4 == 0){
        #pragma unroll
        for (int m = 0; m < 4; m++)
          #pragma unroll
          for (int n = 0; n < 4; n++)
            accP[m][n] = __builtin_amdgcn_mfma_f32_16x16x32_bf16(a[m], b[n], z4, 0, 0, 0);
      } else {
        #pragma unroll
        for (int m = 0; m < 4; m++)
          #pragma unroll
          for (int n = 0; n < 4; n++)
            accP[m][n] = __builtin_amdgcn_mfma_f32_16x16x32_bf16(a[m], b[n], accP[m][n], 0, 0, 0);
      }
      buf ^= 1;
    }
    #pragma unroll
    for (int m = 0; m < 4; m++){
      const f32x4 g4 = *(const f32x4*)&gl2[pb * 132 + wr + m * 16 + l4 * 4];
      #pragma unroll
      for (int n = 0; n < 4; n++)
        accT[m][n] += g4 * accP[m][n];
    }
  }

  #pragma unroll
  for (int n = 0; n < 4; n++){
    const int col = q * 128 + wc + n * 16 + l15;
    const float bv = bias[col];
    #pragma unroll
    for (int m = 0; m < 4; m++){
      #pragma unroll
      for (int r = 0; r < 4; r++){
        const int row = b0 + wr + m * 16 + l4 * 4 + r;
        out[(size_t)row * DOUT + col] = accT[m][n][r] + bv;
      }
    }
  }
}

// ---------------- launch -----------------------------------------------------
extern "C" void kernel_launch(void* const* d_in, const int* in_sizes, int n_in,
                              void* d_out, int out_size, void* d_ws, size_t ws_size,
                              hipStream_t stream)
{
  const float* x    = (const float*)d_in[0];
  const float* w    = (const float*)d_in[1];
  const float* bias = (const float*)d_in[2];
  const float* gw   = (const float*)d_in[3];
  const float* gb   = (const float*)d_in[4];
  float* out = (float*)d_out;

  // ws (<=50.1 MiB):
  //   [0,8M)   part split 0 (becomes final gates)
  //   [8,16M)  part split 1 (dead after topk) -> wtt (tiled W^T) after refine
  //   [16,48M) xht tiled bf16(x)
  //   [48,49M) ght | [49,50M) glt | [50M,+32K) flags
  // xlt (32 MB) lives in d_out scratch space: written by conv_xhl, read only
  // by gate_v5, then d_out fully overwritten by main_v4.
  char* wsb = (char*)d_ws;
  float*          part = (float*)wsb;
  unsigned short* wtt  = (unsigned short*)(wsb + (size_t)8  * 1024 * 1024);
  unsigned short* xht  = (unsigned short*)(wsb + (size_t)16 * 1024 * 1024);
  unsigned short* ght  = (unsigned short*)(wsb + (size_t)48 * 1024 * 1024);
  unsigned short* glt  = (unsigned short*)(wsb + (size_t)49 * 1024 * 1024);
  int*            flg  = (int*)           (wsb + (size_t)50 * 1024 * 1024);
  unsigned short* xlt  = (unsigned short*)d_out;

  conv_xhl <<<dim3(BATCH / 64, DIN / 128), 256, 0, stream>>>(x, xht, xlt);
  conv_gwt2<<<dim3(DIN / 64, NB / 64), 256, 0, stream>>>(gw, ght, glt);
  gate_v5  <<<dim3(BATCH / 128, NB / 64, 2), 256, 0, stream>>>(xht, xlt, ght, glt, part);
  topk     <<<BATCH / 4, 256, 0, stream>>>(part, gb, flg);
  refine   <<<BATCH / 4, 256, 0, stream>>>(x, gw, gb, flg, part);
  conv_wt2 <<<dim3(DIN / 64, DOUT / 64), 256, 0, stream>>>(w, wtt);
  main_v4  <<<1024, 256, 0, stream>>>(xht, wtt, part, bias, out);
}

// Round 11
// 283.016 us; speedup vs baseline: 1.0807x; 1.0807x over previous
//
#include <hip/hip_runtime.h>
#include <hip/hip_bf16.h>
#include <stdint.h>

#define BATCH  8192
#define DIN    2048
#define DOUT   2048
#define NB     256
#define KSEL   26      // ceil(0.1*256)
#define GDELTA 1e-4f   // top-k boundary refine threshold

typedef __attribute__((ext_vector_type(4))) float f32x4;
typedef __attribute__((ext_vector_type(8))) __bf16 bf16x8;
typedef __attribute__((ext_vector_type(8))) unsigned short u16x8;

__device__ __forceinline__ float bf2f(unsigned short u){
  union { unsigned int i; float f; } v; v.i = ((unsigned int)u) << 16; return v.f;
}
__device__ __forceinline__ unsigned short f2bf_c(float f){
  __bf16 b = (__bf16)f;
  union { __bf16 b; unsigned short u; } v; v.b = b; return v.u;
}
// async global->LDS, 16B/lane; LDS dest wave-uniform base.
__device__ __forceinline__ void gload16(const unsigned short* g, unsigned short* l){
  __builtin_amdgcn_global_load_lds(
      (const __attribute__((address_space(1))) void*)g,
      (__attribute__((address_space(3))) void*)l, 16, 0, 0);
}

// BK=32 tile images (T21): elem (row, k) of a [R][32] bf16 tile at u16 offset
// row*32 + ((c3 ^ ((row>>1)&3))<<3) + (k&7), c3 = (k&31)>>3. Frag reads
// (16 rows x b128) land 2-way per bank = free. Same image in global so
// global_load_lds with linear dest reproduces it byte-for-byte.

// ---------------- K0a: x -> tiled hi/lo bf16 (xht = bf16(x), xlt = resid) ---
__global__ __launch_bounds__(256) void conv_xhl(const float* __restrict__ x,
    unsigned short* __restrict__ xht, unsigned short* __restrict__ xlt)
{
  const int r    = threadIdx.x >> 2;        // 0..63
  const int cq   = threadIdx.x & 3;
  const int grow = blockIdx.x * 64 + r;
  const int kp   = (blockIdx.y << 2) + cq;  // global 32k-step 0..63
  const int lrow = grow & 127;
  const int sw   = (lrow >> 1) & 3;
  const size_t base = ((size_t)(grow >> 7) * 64 + kp) * 4096 + lrow * 32;
  const float* xp = &x[(size_t)grow * DIN + kp * 32];
  #pragma unroll
  for (int c3 = 0; c3 < 4; c3++){
    f32x4 a0 = *(const f32x4*)(xp + c3 * 8);
    f32x4 a1 = *(const f32x4*)(xp + c3 * 8 + 4);
    u16x8 hi, lo;
    #pragma unroll
    for (int j = 0; j < 4; j++){
      const __bf16 h0 = (__bf16)a0[j];
      const __bf16 h1 = (__bf16)a1[j];
      union { __bf16 b; unsigned short u; } u0, u1; u0.b = h0; u1.b = h1;
      hi[j] = u0.u; hi[4 + j] = u1.u;
      lo[j]     = f2bf_c(a0[j] - (float)h0);
      lo[4 + j] = f2bf_c(a1[j] - (float)h1);
    }
    const int off = (c3 ^ sw) << 3;
    *(u16x8*)&xht[base + off] = hi;
    *(u16x8*)&xlt[base + off] = lo;
  }
}

// ---------------- K0b: W -> tiled-swizzled bf16 [q][kp][128*32] -------------
__global__ __launch_bounds__(256) void conv_wt2(const float* __restrict__ w,
                                                unsigned short* __restrict__ wtt)
{
  __shared__ float tl[64][65];
  const int k0 = blockIdx.x * 64;
  const int n0 = blockIdx.y * 64;
  const int c  = threadIdx.x & 63;
  const int r4 = threadIdx.x >> 6;
  #pragma unroll
  for (int i = 0; i < 16; i++){
    const int r = r4 * 16 + i;
    tl[r][c] = w[(size_t)(k0 + r) * DOUT + n0 + c];
  }
  __syncthreads();
  const int n  = threadIdx.x & 63;
  const int cp = threadIdx.x >> 6;
  const int gn = n0 + n;
  const int q  = gn >> 7;
  const int ln = gn & 127;
  const int sw = (ln >> 1) & 3;
  #pragma unroll
  for (int u = 0; u < 2; u++){
    const int cc = cp * 2 + u;              // 8k-chunk within 64k
    const int kp = (k0 >> 5) + (cc >> 2);
    const int c3 = cc & 3;
    u16x8 o;
    #pragma unroll
    for (int j = 0; j < 8; j++) o[j] = f2bf_c(tl[cc * 8 + j][n]);
    *(u16x8*)&wtt[((size_t)q * 64 + kp) * 4096 + ln * 32 + ((c3 ^ sw) << 3)] = o;
  }
}

// ---------------- K0c: gw -> tiled-swizzled hi/lo [ct][kp][64*32] -----------
__global__ __launch_bounds__(256) void conv_gwt2(const float* __restrict__ gw,
    unsigned short* __restrict__ ght, unsigned short* __restrict__ glt)
{
  __shared__ float tl[64][65];
  const int k0 = blockIdx.x * 64;
  const int c0 = blockIdx.y * 64;
  const int c  = threadIdx.x & 63;
  const int r4 = threadIdx.x >> 6;
  #pragma unroll
  for (int i = 0; i < 16; i++){
    const int r = r4 * 16 + i;
    tl[r][c] = gw[(size_t)(k0 + r) * NB + c0 + c];
  }
  __syncthreads();
  const int ln = threadIdx.x & 63;
  const int cp = threadIdx.x >> 6;
  const int ct = blockIdx.y;
  const int sw = (ln >> 1) & 3;
  #pragma unroll
  for (int u = 0; u < 2; u++){
    const int cc = cp * 2 + u;
    const int kp = (k0 >> 5) + (cc >> 2);
    const int c3 = cc & 3;
    u16x8 hi, lo;
    #pragma unroll
    for (int j = 0; j < 8; j++){
      const float v = tl[cc * 8 + j][ln];
      const __bf16 hb = (__bf16)v;
      union { __bf16 b; unsigned short u; } uh; uh.b = hb;
      hi[j] = uh.u;
      lo[j] = f2bf_c(v - (float)hb);
    }
    const size_t base = ((size_t)ct * 64 + kp) * 2048 + ln * 32;
    const int off = (c3 ^ sw) << 3;
    *(u16x8*)&ght[base + off] = hi;
    *(u16x8*)&glt[base + off] = lo;
  }
}

// ---------------- K1: gate GEMM, BK=64 single-buffer pure-DMA ---------------
// Block 128b x 64c, 4 waves (64b x 32c), 48 MFMA per wave per drain (vs 24 in
// v5). LDS 48KB single-buffer -> 3 blocks/CU; cross-block TLP covers the
// vmcnt(0) drain (m97/m114 mechanism). MFMA chain order identical to R10.
__global__ __launch_bounds__(256) void gate_v6(
    const unsigned short* __restrict__ xht,
    const unsigned short* __restrict__ xlt,
    const unsigned short* __restrict__ ght,
    const unsigned short* __restrict__ glt,
    float* __restrict__ part)
{
  __shared__ unsigned short Ah[8192], Al[8192];  // 2 BK=32 images each: 32 KB
  __shared__ unsigned short Bh[4096], Bl[4096];  // 16 KB

  const int bt   = blockIdx.x;
  const int b0   = bt * 128;
  const int ct   = blockIdx.y;
  const int z    = blockIdx.z;
  const int t    = threadIdx.x;
  const int lane = t & 63;
  const int wid  = t >> 6;
  const int bw   = wid & 1;
  const int cw   = wid >> 1;
  const int l15  = lane & 15;
  const int l4   = lane >> 4;

  const unsigned short* axh = xht + ((size_t)bt * 64 + z * 32) * 4096;
  const unsigned short* axl = xlt + ((size_t)bt * 64 + z * 32) * 4096;
  const unsigned short* bgh = ght + ((size_t)ct * 64 + z * 32) * 2048;
  const unsigned short* bgl = glt + ((size_t)ct * 64 + z * 32) * 2048;

  f32x4 acc[4][2];
  #pragma unroll
  for (int m = 0; m < 4; m++)
    #pragma unroll
    for (int n = 0; n < 2; n++) acc[m][n] = (f32x4)0.0f;

  int aoff[2][4], boff[2][2];
  #pragma unroll
  for (int ksi = 0; ksi < 2; ksi++){
    #pragma unroll
    for (int m = 0; m < 4; m++){
      const int row = bw * 64 + m * 16 + l15;
      aoff[ksi][m] = ksi * 4096 + row * 32 + ((l4 ^ ((row >> 1) & 3)) << 3);
    }
    #pragma unroll
    for (int n = 0; n < 2; n++){
      const int row = cw * 32 + n * 16 + l15;
      boff[ksi][n] = ksi * 2048 + row * 32 + ((l4 ^ ((row >> 1) & 3)) << 3);
    }
  }

  auto GLOAD = [&](int s){                 // stage 2 consecutive BK=32 images
    const size_t sa = (size_t)s * 8192;    // A: 16KB hi + 16KB lo
    const size_t sb = (size_t)s * 4096;    // B: 8KB hi + 8KB lo
    #pragma unroll
    for (int i = 0; i < 4; i++){
      const int sl = (wid * 4 + i) * 512;
      gload16(axh + sa + sl + lane * 8, &Ah[sl]);
      gload16(axl + sa + sl + lane * 8, &Al[sl]);
    }
    #pragma unroll
    for (int i = 0; i < 2; i++){
      const int sl = (wid * 2 + i) * 512;
      gload16(bgh + sb + sl + lane * 8, &Bh[sl]);
      gload16(bgl + sb + sl + lane * 8, &Bl[sl]);
    }
  };

  #pragma unroll 1
  for (int s = 0; s < 16; s++){
    __syncthreads();                       // prev compute done (LDS free)
    GLOAD(s);
    __syncthreads();                       // DMA drained (vmcnt(0) + barrier)
    #pragma unroll
    for (int ksi = 0; ksi < 2; ksi++){
      bf16x8 ah[4], al[4], bh[2], bl[2];
      #pragma unroll
      for (int m = 0; m < 4; m++){
        ah[m] = *(const bf16x8*)&Ah[aoff[ksi][m]];
        al[m] = *(const bf16x8*)&Al[aoff[ksi][m]];
      }
      #pragma unroll
      for (int n = 0; n < 2; n++){
        bh[n] = *(const bf16x8*)&Bh[boff[ksi][n]];
        bl[n] = *(const bf16x8*)&Bl[boff[ksi][n]];
      }
      #pragma unroll
      for (int m = 0; m < 4; m++)
        #pragma unroll
        for (int n = 0; n < 2; n++){
          acc[m][n] = __builtin_amdgcn_mfma_f32_16x16x32_bf16(ah[m], bh[n], acc[m][n], 0, 0, 0);
          acc[m][n] = __builtin_amdgcn_mfma_f32_16x16x32_bf16(al[m], bh[n], acc[m][n], 0, 0, 0);
          acc[m][n] = __builtin_amdgcn_mfma_f32_16x16x32_bf16(ah[m], bl[n], acc[m][n], 0, 0, 0);
        }
    }
  }

  float* dst = part + (size_t)z * BATCH * NB;
  #pragma unroll
  for (int m = 0; m < 4; m++){
    const int brow = b0 + bw * 64 + m * 16 + l4 * 4;
    #pragma unroll
    for (int n = 0; n < 2; n++){
      const int ccol = ct * 64 + cw * 32 + n * 16 + l15;
      #pragma unroll
      for (int r = 0; r < 4; r++)
        dst[(size_t)(brow + r) * NB + ccol] = acc[m][n][r];
    }
  }
}

// ---------------- K2: sum 2 partials, top-26 + renorm + boundary flag -------
__global__ __launch_bounds__(256) void topk(float* __restrict__ part,
    const float* __restrict__ gb, int* __restrict__ flags)
{
  const int lane = threadIdx.x & 63;
  const int row  = blockIdx.x * 4 + (threadIdx.x >> 6);
  f32x4* p0 = (f32x4*)&part[(size_t)row * NB];
  const f32x4* p1 = (const f32x4*)&part[(size_t)(BATCH + row) * NB];
  const f32x4* gbv = (const f32x4*)gb;
  f32x4 v = p0[lane] + p1[lane] + gbv[lane];

  const float NEG = -3.402823466e38f;
  float w0 = v[0], w1 = v[1], w2 = v[2], w3 = v[3];
  float thr = 0.f, nxt = 0.f;
  for (int it = 0; it < KSEL + 1; it++){
    float lm = fmaxf(fmaxf(w0, w1), fmaxf(w2, w3));
    float wm = lm;
    #pragma unroll
    for (int off = 32; off; off >>= 1) wm = fmaxf(wm, __shfl_xor(wm, off, 64));
    unsigned long long ball = __ballot(lm == wm);
    int first = __ffsll(ball) - 1;
    if (lane == first){
      if      (w0 == wm) w0 = NEG;
      else if (w1 == wm) w1 = NEG;
      else if (w2 == wm) w2 = NEG;
      else               w3 = NEG;
    }
    if (it < KSEL) thr = wm; else nxt = wm;
  }
  if (lane == 0) flags[row] = (thr - nxt < GDELTA) ? 1 : 0;

  float s = 0.f;
  #pragma unroll
  for (int j = 0; j < 4; j++) s += (v[j] >= thr) ? v[j] : 0.f;
  #pragma unroll
  for (int off = 32; off; off >>= 1) s += __shfl_xor(s, off, 64);
  const float d = s * (1.0f / NB);
  f32x4 o;
  #pragma unroll
  for (int j = 0; j < 4; j++) o[j] = (v[j] >= thr) ? v[j] / d : 0.f;
  p0[lane] = o;
}

// ---------------- K2b: exact recompute of boundary-ambiguous rows -----------
__global__ __launch_bounds__(256) void refine(
    const float* __restrict__ x, const float* __restrict__ gw,
    const float* __restrict__ gb, const int* __restrict__ flags,
    float* __restrict__ part)
{
  const int lane = threadIdx.x & 63;
  const int row  = blockIdx.x * 4 + (threadIdx.x >> 6);
  if (!flags[row]) return;

  f32x4 acc0 = (f32x4)0.f, acc1 = (f32x4)0.f;
  const float* xp = &x[(size_t)row * DIN];
  #pragma unroll 8
  for (int k = 0; k < 1024; k++){
    const float xv = xp[k];
    const f32x4 wv = *(const f32x4*)&gw[(size_t)k * NB + lane * 4];
    #pragma unroll
    for (int j = 0; j < 4; j++) acc0[j] = fmaf(xv, wv[j], acc0[j]);
  }
  #pragma unroll 8
  for (int k = 1024; k < 2048; k++){
    const float xv = xp[k];
    const f32x4 wv = *(const f32x4*)&gw[(size_t)k * NB + lane * 4];
    #pragma unroll
    for (int j = 0; j < 4; j++) acc1[j] = fmaf(xv, wv[j], acc1[j]);
  }
  const f32x4 gbv = *(const f32x4*)&gb[lane * 4];
  f32x4 v;
  #pragma unroll
  for (int j = 0; j < 4; j++) v[j] = acc0[j] + acc1[j] + gbv[j];

  const float NEG = -3.402823466e38f;
  float w0 = v[0], w1 = v[1], w2 = v[2], w3 = v[3];
  float thr = 0.f;
  for (int it = 0; it < KSEL; it++){
    float lm = fmaxf(fmaxf(w0, w1), fmaxf(w2, w3));
    float wm = lm;
    #pragma unroll
    for (int off = 32; off; off >>= 1) wm = fmaxf(wm, __shfl_xor(wm, off, 64));
    unsigned long long ball = __ballot(lm == wm);
    int first = __ffsll(ball) - 1;
    if (lane == first){
      if      (w0 == wm) w0 = NEG;
      else if (w1 == wm) w1 = NEG;
      else if (w2 == wm) w2 = NEG;
      else               w3 = NEG;
    }
    thr = wm;
  }
  float s = 0.f;
  #pragma unroll
  for (int j = 0; j < 4; j++) s += (v[j] >= thr) ? v[j] : 0.f;
  #pragma unroll
  for (int off = 32; off; off >>= 1) s += __shfl_xor(s, off, 64);
  const float d = s * (1.0f / NB);
  f32x4 o;
  #pragma unroll
  for (int j = 0; j < 4; j++) o[j] = (v[j] >= thr) ? v[j] / d : 0.f;
  *(f32x4*)&part[(size_t)row * NB + lane * 4] = o;
}

// ---------------- K3: main GEMM, BK=64 dbuf gload_lds + cheap p-fold --------
// v3's pipeline (32 MFMA per drain, double-buffered DMA) + v4's fold (gl2
// [p][row] b128 reads, zero-C first MFMA of p-slice). 128b x 128n, 4 waves.
__global__ __launch_bounds__(256) void main_v5(
    const unsigned short* __restrict__ xht,
    const unsigned short* __restrict__ wtt,
    const float* __restrict__ g,
    const float* __restrict__ bias,
    float* __restrict__ out)
{
  __shared__ unsigned short XA[2][8192], WB[2][8192];  // 64 KB
  __shared__ float gl2[16 * 132];                      // [p][row], 8.4 KB

  const int f  = blockIdx.x;
  const int q  = f >> 6;
  const int bt = (f & 7) * 8 + ((f >> 3) & 7);   // XCD-aware: q-mates co-XCD
  const int b0 = bt * 128;
  const int t    = threadIdx.x;
  const int lane = t & 63;
  const int wid  = t >> 6;
  const int wr   = (wid >> 1) * 64;
  const int wc   = (wid & 1) * 64;
  const int l15  = lane & 15;
  const int l4   = lane >> 4;

  for (int e = t; e < 16 * 128; e += 256){
    const int p = e >> 7, r = e & 127;
    gl2[p * 132 + r] = g[(size_t)(b0 + r) * NB + p * 16 + q];
  }

  f32x4 accT[4][4];
  #pragma unroll
  for (int m = 0; m < 4; m++)
    #pragma unroll
    for (int n = 0; n < 4; n++) accT[m][n] = (f32x4)0.0f;
  const f32x4 z4 = (f32x4)0.0f;

  int aoff[2][4], boff[2][4];
  #pragma unroll
  for (int ksi = 0; ksi < 2; ksi++){
    #pragma unroll
    for (int m = 0; m < 4; m++){
      const int row = wr + m * 16 + l15;
      aoff[ksi][m] = ksi * 4096 + row * 32 + ((l4 ^ ((row >> 1) & 3)) << 3);
    }
    #pragma unroll
    for (int n = 0; n < 4; n++){
      const int row = wc + n * 16 + l15;
      boff[ksi][n] = ksi * 4096 + row * 32 + ((l4 ^ ((row >> 1) & 3)) << 3);
    }
  }

  const unsigned short* asrc0 = xht + (size_t)bt * 64 * 4096;
  const unsigned short* bsrc0 = wtt + (size_t)q  * 64 * 4096;

  auto GLOAD = [&](int bb, int s){       // stage 2 consecutive BK=32 images
    const unsigned short* as = asrc0 + (size_t)s * 8192;
    const unsigned short* bs = bsrc0 + (size_t)s * 8192;
    #pragma unroll
    for (int i = 0; i < 4; i++){
      const int sl = (wid * 4 + i) * 512;
      gload16(as + sl + lane * 8, &XA[bb][sl]);
      gload16(bs + sl + lane * 8, &WB[bb][sl]);
    }
  };

  GLOAD(0, 0);
  int buf = 0;
  #pragma unroll 1
  for (int pb = 0; pb < 16; pb++){
    f32x4 accP[4][4];
    #pragma unroll
    for (int s2 = 0; s2 < 2; s2++){
      const int s = pb * 2 + s2;
      __syncthreads();                  // DMA(buf) drained; prev reads done
      if (s < 31) GLOAD(buf ^ 1, s + 1);
      #pragma unroll
      for (int ksi = 0; ksi < 2; ksi++){
        bf16x8 a[4], b[4];
        #pragma unroll
        for (int m = 0; m < 4; m++) a[m] = *(const bf16x8*)&XA[buf][aoff[ksi][m]];
        #pragma unroll
        for (int n = 0; n < 4; n++) b[n] = *(const bf16x8*)&WB[buf][boff[ksi][n]];
        if (s2 == 0 && ksi == 0){
          #pragma unroll
          for (int m = 0; m < 4; m++)
            #pragma unroll
            for (int n = 0; n < 4; n++)
              accP[m][n] = __builtin_amdgcn_mfma_f32_16x16x32_bf16(a[m], b[n], z4, 0, 0, 0);
        } else {
          #pragma unroll
          for (int m = 0; m < 4; m++)
            #pragma unroll
            for (int n = 0; n < 4; n++)
              accP[m][n] = __builtin_amdgcn_mfma_f32_16x16x32_bf16(a[m], b[n], accP[m][n], 0, 0, 0);
        }
      }
      buf ^= 1;
    }
    #pragma unroll
    for (int m = 0; m < 4; m++){
      const f32x4 g4 = *(const f32x4*)&gl2[pb * 132 + wr + m * 16 + l4 * 4];
      #pragma unroll
      for (int n = 0; n < 4; n++)
        accT[m][n] += g4 * accP[m][n];
    }
  }

  #pragma unroll
  for (int n = 0; n < 4; n++){
    const int col = q * 128 + wc + n * 16 + l15;
    const float bv = bias[col];
    #pragma unroll
    for (int m = 0; m < 4; m++){
      #pragma unroll
      for (int r = 0; r < 4; r++){
        const int row = b0 + wr + m * 16 + l4 * 4 + r;
        out[(size_t)row * DOUT + col] = accT[m][n][r] + bv;
      }
    }
  }
}

// ---------------- launch -----------------------------------------------------
extern "C" void kernel_launch(void* const* d_in, const int* in_sizes, int n_in,
                              void* d_out, int out_size, void* d_ws, size_t ws_size,
                              hipStream_t stream)
{
  const float* x    = (const float*)d_in[0];
  const float* w    = (const float*)d_in[1];
  const float* bias = (const float*)d_in[2];
  const float* gw   = (const float*)d_in[3];
  const float* gb   = (const float*)d_in[4];
  float* out = (float*)d_out;

  // ws (<=50.1 MiB):
  //   [0,8M)   part split 0 (becomes final gates)
  //   [8,16M)  part split 1 (dead after topk) -> wtt (tiled W^T) after refine
  //   [16,48M) xht tiled bf16(x)
  //   [48,49M) ght | [49,50M) glt | [50M,+32K) flags
  // xlt (32 MB) lives in d_out scratch: written by conv_xhl, read by gate_v6,
  // then d_out fully overwritten by main_v5.
  char* wsb = (char*)d_ws;
  float*          part = (float*)wsb;
  unsigned short* wtt  = (unsigned short*)(wsb + (size_t)8  * 1024 * 1024);
  unsigned short* xht  = (unsigned short*)(wsb + (size_t)16 * 1024 * 1024);
  unsigned short* ght  = (unsigned short*)(wsb + (size_t)48 * 1024 * 1024);
  unsigned short* glt  = (unsigned short*)(wsb + (size_t)49 * 1024 * 1024);
  int*            flg  = (int*)           (wsb + (size_t)50 * 1024 * 1024);
  unsigned short* xlt  = (unsigned short*)d_out;

  conv_xhl <<<dim3(BATCH / 64, DIN / 128), 256, 0, stream>>>(x, xht, xlt);
  conv_gwt2<<<dim3(DIN / 64, NB / 64), 256, 0, stream>>>(gw, ght, glt);
  gate_v6  <<<dim3(BATCH / 128, NB / 64, 2), 256, 0, stream>>>(xht, xlt, ght, glt, part);
  topk     <<<BATCH / 4, 256, 0, stream>>>(part, gb, flg);
  refine   <<<BATCH / 4, 256, 0, stream>>>(x, gw, gb, flg, part);
  conv_wt2 <<<dim3(DIN / 64, DOUT / 64), 256, 0, stream>>>(w, wtt);
  main_v5  <<<1024, 256, 0, stream>>>(xht, wtt, part, bias, out);
}